// Round 8
// baseline (485.010 us; speedup 1.0000x reference)
//
#include <hip/hip_runtime.h>

// EncConvNet fused v10: conv7x7s3+sq -> fc1+sq -> fc2, one kernel.
// v9 post-mortem: LDS pipe ~75% busy, dominated by conv's LDS reads (x words
// re-read ~11x: 4 channels x overlapping windows = 21K of 30K LDS cyc/block).
// v10 deletes conv LDS reads entirely: conv reads x DIRECT FROM GLOBAL with
// full-row tiles (every fetched word used; x is L2/L3-warm; c-copies hit L1).
//  - conv roles: tid = c*128 + yph*64 + ypl*32 + g. wave = c*2 + yph ->
//    c wave-uniform -> 49 taps via s_load into SGPRs (spill-proof).
//    Thread computes a 2-row x 8-col tile (rows 2yp, 2yp+1 of channel c,
//    image g): reads rows 6yp..6yp+9 as 7x b128 each (28 words, no waste),
//    784 FMA. Per-output FMA order (rr asc, kx asc) identical to v9 ->
//    bit-identical results. Live set ~52 VGPR: row[28]+accA[8]+accB[8].
//  - No xbuf, no commit/prefetch, conv needs ZERO barriers (3 total now).
//  - LDS = hb[64][33] + h2b[16][33] + w2b + ob = 47616 B -> 3 blocks/CU,
//    24 waves/CU, and LDS traffic drops to fc1-dominated (~9K cyc/block).
//  - fc1/fc2: v9 verbatim (8 waves x 8 outputs redundant + oh-select,
//    s_load weight quads; fc2 via w2b k-major).

#define BLK_IMGS    32
#define HB_PITCH    33                   // float4 pitch (32 imgs + 1 pad)
#define H2_PITCH    33

// LDS float offsets
#define LDS_H       0                    // 64*33*4 = 8448 floats
#define LDS_H2      8448                 // 16*33*4 = 2112 floats
#define LDS_W2      10560                // 1024 floats
#define LDS_OUT     11584                // 320 floats
#define LDS_TOTAL_F 11904                // 47616 bytes -> 3 blocks/CU

__global__ __launch_bounds__(512)
void encconv_fused10(const float* __restrict__ x,
                     const float* __restrict__ conv_w,
                     const float* __restrict__ conv_b,
                     const float* __restrict__ fc1_w,
                     const float* __restrict__ fc1_b,
                     const float* __restrict__ fc2_w,
                     const float* __restrict__ fc2_b,
                     float* __restrict__ out)
{
    extern __shared__ float lds[];
    float4* hb  = (float4*)(lds + LDS_H);
    float4* h2b = (float4*)(lds + LDS_H2);
    float4* w2b = (float4*)(lds + LDS_W2);
    float*  ob  = lds + LDS_OUT;

    const int tid  = threadIdx.x;
    const int blk  = blockIdx.x;
    const long base_img = (long)blk * BLK_IMGS;

    const int lane = tid & 63;
    const int wv   = tid >> 6;       // wave 0..7

    // ---- conv roles: wave = c*2 + yph (c wave-uniform) ----
    //      lane = ypl*32 + g ; yp = yph*2 + ypl -> output rows 2yp, 2yp+1
    const int c   = __builtin_amdgcn_readfirstlane(wv >> 1);   // 0..3
    const int yph = __builtin_amdgcn_readfirstlane(wv & 1);    // 0..1
    const int ypl = lane >> 5;       // 0..1
    const int yp  = yph * 2 + ypl;   // 0..3
    const int g   = lane & 31;       // image 0..31

    // conv taps: wave-uniform address -> s_load -> SGPRs (zero VGPR cost)
    float ws[49];
    #pragma unroll
    for (int i = 0; i < 49; ++i) ws[i] = conv_w[c * 49 + i];
    const float cb = conv_b[c];

    // stage fc2_w into LDS, k-major: slot = kk*16 + j
    if (tid < 160) {
        float4 v = *(const float4*)(fc2_w + tid * 4);
        int e  = tid * 4;
        int j  = e >> 6;          // 0..9
        int kk = (e & 63) >> 2;   // 0..15
        w2b[kk * 16 + j] = v;
    }

    // ---- conv: 2-row x 8-col tile from global (window rows 6yp..6yp+9) ----
    float accA[8], accB[8];
    #pragma unroll
    for (int i = 0; i < 8; ++i) { accA[i] = 0.f; accB[i] = 0.f; }

    const float* xi = x + (base_img + g) * 784 + yp * 6 * 28;
    #pragma unroll
    for (int wrow = 0; wrow < 10; ++wrow) {
        const float* rp = xi + wrow * 28;        // 112B rows, 16B aligned
        float4 r0 = *(const float4*)(rp + 0);
        float4 r1 = *(const float4*)(rp + 4);
        float4 r2 = *(const float4*)(rp + 8);
        float4 r3 = *(const float4*)(rp + 12);
        float4 r4 = *(const float4*)(rp + 16);
        float4 r5 = *(const float4*)(rp + 20);
        float4 r6 = *(const float4*)(rp + 24);
        float r[28] = { r0.x,r0.y,r0.z,r0.w, r1.x,r1.y,r1.z,r1.w,
                        r2.x,r2.y,r2.z,r2.w, r3.x,r3.y,r3.z,r3.w,
                        r4.x,r4.y,r4.z,r4.w, r5.x,r5.y,r5.z,r5.w,
                        r6.x,r6.y,r6.z,r6.w };
        // row A (y = 2yp): tap row rr = wrow, valid wrow 0..6
        if (wrow <= 6) {
            #pragma unroll
            for (int kx = 0; kx < 7; ++kx) {
                const float wA = ws[wrow * 7 + kx];      // SGPR operand
                #pragma unroll
                for (int col = 0; col < 8; ++col)
                    accA[col] = fmaf(r[3 * col + kx], wA, accA[col]);
            }
        }
        // row B (y = 2yp+1): tap row rr = wrow-3, valid wrow 3..9
        if (wrow >= 3) {
            #pragma unroll
            for (int kx = 0; kx < 7; ++kx) {
                const float wB = ws[(wrow - 3) * 7 + kx];
                #pragma unroll
                for (int col = 0; col < 8; ++col)
                    accB[col] = fmaf(r[3 * col + kx], wB, accB[col]);
            }
        }
    }

    // bias + square -> hb (k-major: k4 = c*16 + y*2 + xh; float4 = 4 cols)
    #pragma unroll
    for (int ty = 0; ty < 2; ++ty) {
        const float* a = ty ? accB : accA;
        const int y = 2 * yp + ty;
        #pragma unroll
        for (int xh = 0; xh < 2; ++xh) {
            float4 hv;
            hv.x = a[4 * xh + 0] + cb; hv.x *= hv.x;
            hv.y = a[4 * xh + 1] + cb; hv.y *= hv.y;
            hv.z = a[4 * xh + 2] + cb; hv.z *= hv.z;
            hv.w = a[4 * xh + 3] + cb; hv.w *= hv.w;
            hb[(c * 16 + y * 2 + xh) * HB_PITCH + g] = hv;
        }
    }
    __syncthreads();   // hb complete (also covers w2b staging)

    // ---- fc1: wave -> outputs 8w..8w+7; lanes = 2 x 32 images ----
    {
        const int img = lane & 31;
        const int oh  = lane >> 5;                                 // 0 or 1
        const int w8  = __builtin_amdgcn_readfirstlane(wv);
        const float* wbase = fc1_w + (w8 * 8) * 256;

        float a0=0.f,a1=0.f,a2=0.f,a3=0.f,a4=0.f,a5=0.f,a6=0.f,a7=0.f;

        #pragma unroll 2
        for (int k4 = 0; k4 < 64; ++k4) {
            float4 h4 = hb[k4 * HB_PITCH + img];          // 512B + 2-lane bcast
            const float* wp = wbase + k4 * 4;
            float4 w0 = *(const float4*)(wp + 0 * 256);   // uniform -> s_load
            float4 w1 = *(const float4*)(wp + 1 * 256);
            float4 w2 = *(const float4*)(wp + 2 * 256);
            float4 w3 = *(const float4*)(wp + 3 * 256);
            float4 w4 = *(const float4*)(wp + 4 * 256);
            float4 w5 = *(const float4*)(wp + 5 * 256);
            float4 w6 = *(const float4*)(wp + 6 * 256);
            float4 w7 = *(const float4*)(wp + 7 * 256);
            a0 = fmaf(h4.x,w0.x,a0); a0 = fmaf(h4.y,w0.y,a0); a0 = fmaf(h4.z,w0.z,a0); a0 = fmaf(h4.w,w0.w,a0);
            a1 = fmaf(h4.x,w1.x,a1); a1 = fmaf(h4.y,w1.y,a1); a1 = fmaf(h4.z,w1.z,a1); a1 = fmaf(h4.w,w1.w,a1);
            a2 = fmaf(h4.x,w2.x,a2); a2 = fmaf(h4.y,w2.y,a2); a2 = fmaf(h4.z,w2.z,a2); a2 = fmaf(h4.w,w2.w,a2);
            a3 = fmaf(h4.x,w3.x,a3); a3 = fmaf(h4.y,w3.y,a3); a3 = fmaf(h4.z,w3.z,a3); a3 = fmaf(h4.w,w3.w,a3);
            a4 = fmaf(h4.x,w4.x,a4); a4 = fmaf(h4.y,w4.y,a4); a4 = fmaf(h4.z,w4.z,a4); a4 = fmaf(h4.w,w4.w,a4);
            a5 = fmaf(h4.x,w5.x,a5); a5 = fmaf(h4.y,w5.y,a5); a5 = fmaf(h4.z,w5.z,a5); a5 = fmaf(h4.w,w5.w,a5);
            a6 = fmaf(h4.x,w6.x,a6); a6 = fmaf(h4.y,w6.y,a6); a6 = fmaf(h4.z,w6.z,a6); a6 = fmaf(h4.w,w6.w,a6);
            a7 = fmaf(h4.x,w7.x,a7); a7 = fmaf(h4.y,w7.y,a7); a7 = fmaf(h4.z,w7.z,a7); a7 = fmaf(h4.w,w7.w,a7);
        }

        // lane keeps half oh: one-time select, then bias + square
        const float* bp = fc1_b + w8 * 8;   // uniform -> s_load
        float s0 = oh ? a4 : a0;  float b0 = oh ? bp[4] : bp[0];
        float s1 = oh ? a5 : a1;  float b1 = oh ? bp[5] : bp[1];
        float s2 = oh ? a6 : a2;  float b2 = oh ? bp[6] : bp[2];
        float s3 = oh ? a7 : a3;  float b3 = oh ? bp[7] : bp[3];
        float4 p0;
        p0.x = s0 + b0; p0.x *= p0.x;
        p0.y = s1 + b1; p0.y *= p0.y;
        p0.z = s2 + b2; p0.z *= p0.z;
        p0.w = s3 + b3; p0.w *= p0.w;
        h2b[(w8 * 2 + oh) * H2_PITCH + img] = p0;
    }
    __syncthreads();

    // ---- fc2: thread (im5 = tid>>4, q = tid&15), active q<10 ----
    {
        const int im5 = tid >> 4;     // 0..31
        const int q   = tid & 15;
        if (q < 10) {
            float s = 0.f;
            #pragma unroll
            for (int k4 = 0; k4 < 16; ++k4) {
                float4 hh = h2b[k4 * H2_PITCH + im5];
                float4 wA = w2b[k4 * 16 + q];
                s = fmaf(hh.x, wA.x, s); s = fmaf(hh.y, wA.y, s);
                s = fmaf(hh.z, wA.z, s); s = fmaf(hh.w, wA.w, s);
            }
            ob[im5 * 10 + q] = s + fc2_b[q];
        }
    }
    __syncthreads();

    // ---- coalesced output store: 320 floats per block ----
    if (tid < 80) {
        float4 v = *(const float4*)(ob + tid * 4);
        *(float4*)(out + (long)blk * 320 + tid * 4) = v;
    }
}

extern "C" void kernel_launch(void* const* d_in, const int* in_sizes, int n_in,
                              void* d_out, int out_size, void* d_ws, size_t ws_size,
                              hipStream_t stream) {
    const float* x      = (const float*)d_in[0];
    const float* conv_w = (const float*)d_in[1];
    const float* conv_b = (const float*)d_in[2];
    const float* fc1_w  = (const float*)d_in[3];
    const float* fc1_b  = (const float*)d_in[4];
    const float* fc2_w  = (const float*)d_in[5];
    const float* fc2_b  = (const float*)d_in[6];
    float* out = (float*)d_out;

    const int B = in_sizes[0] / 784;
    const int blocks = (B + BLK_IMGS - 1) / BLK_IMGS;      // 2048 for B=65536
    const size_t lds_bytes = LDS_TOTAL_F * sizeof(float);  // 47616 B

    encconv_fused10<<<blocks, 512, lds_bytes, stream>>>(
        x, conv_w, conv_b, fc1_w, fc1_b, fc2_w, fc2_b, out);
}